// Round 9
// baseline (489.850 us; speedup 1.0000x reference)
//
#include <hip/hip_runtime.h>
#include <hip/hip_cooperative_groups.h>

namespace cg = cooperative_groups;

#define N_NODES 100000
#define N_EDGES 400000
#define D 128
#define BN_EPS 1e-5f
#define ELL_CAP 32

#define NSTAT 64                                     // striped stat copies
#define CS_BLOCKS 625                                // colstats role: 625 blocks x 256 = 160000 threads
#define CS_ITER 20                                   // 3.2M float4 / 160k = exactly 20/thread
#define FILL_BLOCKS 1563                             // fallback fill grid
#define MEGA_BLOCKS 1024                             // 4 blocks/CU x 256 CU (cooperative co-residency)
#define FILL_ROLE_THREADS (383 * 256)                // 98048 threads in mega fill role
#define N_TILES 1563                                 // gemm tiles of 64 rows

// ===== primary (ELL2/fp16-h) ws layout, 4B units =====
#define WS_STATS   0                                 // NSTAT*256 floats (64KB)
#define WS_HB      (NSTAT * 256)                     // N*D fp16 = 6.4M float slots
#define WS_DEG2    (WS_HB + N_NODES * D / 2)         // 100000 ints
#define WS_ELL2    (WS_DEG2 + N_NODES)               // N*ELL_CAP int2 = 6.4M ints
#define WS_ELL2_END (WS_ELL2 + N_NODES * ELL_CAP * 2)
#define WS_WB      WS_ELL2_END                       // W as bf16: 16384 ushort = 8192 slots
#define WS_ELL_END2 (WS_WB + 8192)
// ===== CSR fallback layout (proven R3) =====
#define WS_SCALE   (NSTAT * 256)
#define WS_SHIFT   (WS_SCALE + 128)
#define WS_WT      (WS_SHIFT + 128)
#define WS_H       (WS_WT + D * D)
#define WS_DEG     (WS_H + N_NODES * D)
#define WS_ROWPTR  (WS_DEG + N_NODES)
#define WS_CURSOR  (WS_ROWPTR + N_NODES + 1)
#define WS_CSRCOL  (WS_CURSOR + N_NODES)
#define WS_CSRW    (WS_CSRCOL + N_EDGES)
#define WS_END     (WS_CSRW + N_EDGES)

typedef __attribute__((ext_vector_type(8))) short short8;
typedef __attribute__((ext_vector_type(4))) float f32x4;

static __device__ __forceinline__ unsigned short f2bf(float f) {
    union { float f; unsigned u; } v; v.f = f;
    unsigned r = v.u + 0x7FFF + ((v.u >> 16) & 1);   // RNE
    return (unsigned short)(r >> 16);
}
static __device__ __forceinline__ float bf2f(unsigned short b) {
    union { unsigned u; float f; } v; v.u = ((unsigned)b) << 16;
    return v.f;
}
static __device__ __forceinline__ unsigned short f2h(float f) {
    union { _Float16 h; unsigned short u; } v; v.h = (_Float16)f;   // v_cvt_f16_f32, RNE
    return v.u;
}
static __device__ __forceinline__ float h2f(unsigned short u) {
    union { unsigned short u; _Float16 h; } v; v.u = u;
    return (float)v.h;
}

#define YPAD 136

// ================= MEGA cooperative kernel: all 4 phases, 1 dispatch =================
// R8 post-mortem: a 64KB memset profiled at 42.5us -> ~40us per-dispatch floor dominates;
// 5 serial dispatches = the real cost. One cooperative kernel with grid.sync between phases.
// 1024 blocks x 256 thr = exactly 4 blocks/CU (LDS 26.4KB, VGPR<=128 via launch bounds).
__global__ __launch_bounds__(256, 4) void mega_kernel(const float* __restrict__ x,
                                                      float* __restrict__ stats,
                                                      const int* __restrict__ ei,
                                                      const float* __restrict__ ew,
                                                      int* __restrict__ deg,
                                                      int2* __restrict__ ell2,
                                                      const float* __restrict__ W,
                                                      unsigned short* __restrict__ Wb,
                                                      const float* __restrict__ gamma,
                                                      const float* __restrict__ beta,
                                                      unsigned short* __restrict__ hh,
                                                      float* __restrict__ out) {
    cg::grid_group grid = cg::this_grid();
    __shared__ float4 ss[256];
    __shared__ float4 sq[256];
    __shared__ __align__(16) unsigned short Yl[64 * YPAD];
    __shared__ float sscale[128];
    __shared__ float sshift[128];

    int b = blockIdx.x;
    int t = threadIdx.x;
    int gtid = b * 256 + t;

    // ---------- phase 0: zero stats (16384 f) + deg (100000 i); 116384 <= 262144 threads ----------
    if (gtid < NSTAT * 256) stats[gtid] = 0.f;
    {
        int dtid = gtid - NSTAT * 256;
        if (dtid >= 0 && dtid < N_NODES) deg[dtid] = 0;
    }
    grid.sync();

    // ---------- phase 1: colstats (b<625) || ell2-fill (625..1007) || convW (1008..1023) ----------
    if (b < CS_BLOCKS) {
        int tid = b * 256 + t;
        const int NTH = CS_BLOCKS * 256;             // 160000
        const float4* x4 = (const float4*)x;
        float4 v[CS_ITER];
        #pragma unroll
        for (int i = 0; i < CS_ITER; i++) v[i] = x4[tid + i * NTH];
        float4 s = {0.f, 0.f, 0.f, 0.f};
        float4 q = {0.f, 0.f, 0.f, 0.f};
        #pragma unroll
        for (int i = 0; i < CS_ITER; i++) {
            s.x += v[i].x; s.y += v[i].y; s.z += v[i].z; s.w += v[i].w;
            q.x += v[i].x * v[i].x; q.y += v[i].y * v[i].y;
            q.z += v[i].z * v[i].z; q.w += v[i].w * v[i].w;
        }
        ss[t] = s;
        sq[t] = q;
        __syncthreads();
        if (t < 32) {
            float4 a = ss[t];
            float4 bb = sq[t];
            for (int i = 32; i < 256; i += 32) {
                float4 t1 = ss[t + i];
                float4 t2 = sq[t + i];
                a.x += t1.x; a.y += t1.y; a.z += t1.z; a.w += t1.w;
                bb.x += t2.x; bb.y += t2.y; bb.z += t2.z; bb.w += t2.w;
            }
            float* st = stats + (b % NSTAT) * 256;
            int colb = (t * 4) & 127;
            atomicAdd(&st[colb + 0], a.x);
            atomicAdd(&st[colb + 1], a.y);
            atomicAdd(&st[colb + 2], a.z);
            atomicAdd(&st[colb + 3], a.w);
            atomicAdd(&st[128 + colb + 0], bb.x);
            atomicAdd(&st[128 + colb + 1], bb.y);
            atomicAdd(&st[128 + colb + 2], bb.z);
            atomicAdd(&st[128 + colb + 3], bb.w);
        }
    } else if (b < CS_BLOCKS + 383) {
        int base = (b - CS_BLOCKS) * 256 + t;        // 98048 threads, <=5 strided iters
        for (int e = base; e < N_EDGES; e += FILL_ROLE_THREADS) {
            int r = ei[e];
            int c = ei[N_EDGES + e];
            float w = ew[e];
            int slot = atomicAdd(&deg[r], 1);
            if (slot < ELL_CAP) ell2[r * ELL_CAP + slot] = make_int2(c, __float_as_int(w));
        }
    } else {
        int i = (b - CS_BLOCKS - 383) * 256 + t;     // 16 blocks x 256 = 4096 float4 groups
        float4 v = *(const float4*)(W + i * 4);
        ushort4 o;
        o.x = f2bf(v.x); o.y = f2bf(v.y); o.z = f2bf(v.z); o.w = f2bf(v.w);
        *(ushort4*)(Wb + i * 4) = o;
    }
    grid.sync();

    // ---------- phase 2: gemm (finalize once per block, then tiles b and b+1024) ----------
    {
        if (t < 128) {
            float sum = 0.f, sq2 = 0.f;
            #pragma unroll 16
            for (int c = 0; c < NSTAT; c++) {
                sum += stats[c * 256 + t];
                sq2 += stats[c * 256 + 128 + t];
            }
            float mu  = sum * (1.0f / N_NODES);
            float var = sq2 * (1.0f / N_NODES) - mu * mu;
            float sc  = gamma[t] * rsqrtf(var + BN_EPS);
            sscale[t] = sc;
            sshift[t] = beta[t] - mu * sc;
        }
        __syncthreads();

        int lane = t & 63;
        int wave = t >> 6;
        int m16  = lane & 15;
        int quad = lane >> 4;
        int wrow0 = wave * 16;
        int c4 = (t & 31) * 4;
        float4 sc = *(const float4*)(sscale + c4);
        float4 sh = *(const float4*)(sshift + c4);

        for (int tile = b; tile < N_TILES; tile += MEGA_BLOCKS) {
            int row0 = tile * 64;
            float4 xv[8];
            #pragma unroll
            for (int p = 0; p < 8; p++) {
                int r = (t + p * 256) >> 5;
                int grow = row0 + r;
                int srow = grow < N_NODES ? grow : N_NODES - 1;
                xv[p] = *(const float4*)(x + (size_t)srow * D + c4);
            }
            #pragma unroll
            for (int p = 0; p < 8; p++) {
                int r = (t + p * 256) >> 5;
                ushort4 y;
                y.x = f2bf(fmaxf(fmaf(xv[p].x, sc.x, sh.x), 0.f));
                y.y = f2bf(fmaxf(fmaf(xv[p].y, sc.y, sh.y), 0.f));
                y.z = f2bf(fmaxf(fmaf(xv[p].z, sc.z, sh.z), 0.f));
                y.w = f2bf(fmaxf(fmaf(xv[p].w, sc.w, sh.w), 0.f));
                *(ushort4*)(Yl + r * YPAD + c4) = y;
            }
            __syncthreads();

            f32x4 acc[8];
            #pragma unroll
            for (int nt = 0; nt < 8; nt++) acc[nt] = (f32x4){0.f, 0.f, 0.f, 0.f};

            const unsigned short* wb = Wb + m16 * D + quad * 8;    // B[k][n]=Wb[n][k]
            const unsigned short* yl = Yl + (wrow0 + m16) * YPAD + quad * 8;
            #pragma unroll
            for (int kc = 0; kc < 4; kc++) {
                short8 a = *(const short8*)(yl + kc * 32);
                #pragma unroll
                for (int nt = 0; nt < 8; nt++) {
                    short8 bb = *(const short8*)(wb + nt * 16 * D + kc * 32);
                    acc[nt] = __builtin_amdgcn_mfma_f32_16x16x32_bf16(a, bb, acc[nt], 0, 0, 0);
                }
            }
            #pragma unroll
            for (int r = 0; r < 4; r++) {
                int grow = row0 + wrow0 + quad * 4 + r;
                if (grow < N_NODES) {
                    unsigned short* hrow = hh + (size_t)grow * D + m16;
                    #pragma unroll
                    for (int nt = 0; nt < 8; nt++) {
                        hrow[nt * 16] = f2h(acc[nt][r]);
                    }
                }
            }
            __syncthreads();   // Yl safe for next tile
        }
    }
    grid.sync();

    // ---------- phase 3: gather (16 lanes/node, 4-deep ILP, nt out stores) ----------
    {
        int lane = t & 15;
        for (int n = b * 16 + (t >> 4); n < N_NODES; n += MEGA_BLOCKS * 16) {
            short8 hself = *(const short8*)(hh + (size_t)n * D + lane * 8);
            int dg = deg[n];
            if (dg > ELL_CAP) dg = ELL_CAP;
            int dg16 = dg < 16 ? dg : 16;

            int2 my = make_int2(0, 0);
            if (lane < dg16) my = ell2[n * ELL_CAP + lane];

            float acc[8] = {0.f, 0.f, 0.f, 0.f, 0.f, 0.f, 0.f, 0.f};
            int s = 0;
            for (; s + 4 <= dg16; s += 4) {
                int   c0 = __shfl(my.x, s + 0, 16); float w0 = __int_as_float(__shfl(my.y, s + 0, 16));
                int   c1 = __shfl(my.x, s + 1, 16); float w1 = __int_as_float(__shfl(my.y, s + 1, 16));
                int   c2 = __shfl(my.x, s + 2, 16); float w2 = __int_as_float(__shfl(my.y, s + 2, 16));
                int   c3 = __shfl(my.x, s + 3, 16); float w3 = __int_as_float(__shfl(my.y, s + 3, 16));
                short8 v0 = *(const short8*)(hh + (size_t)c0 * D + lane * 8);
                short8 v1 = *(const short8*)(hh + (size_t)c1 * D + lane * 8);
                short8 v2 = *(const short8*)(hh + (size_t)c2 * D + lane * 8);
                short8 v3 = *(const short8*)(hh + (size_t)c3 * D + lane * 8);
                #pragma unroll
                for (int j = 0; j < 8; j++) {
                    acc[j] = fmaf(w0, h2f((unsigned short)v0[j]), acc[j]);
                    acc[j] = fmaf(w1, h2f((unsigned short)v1[j]), acc[j]);
                    acc[j] = fmaf(w2, h2f((unsigned short)v2[j]), acc[j]);
                    acc[j] = fmaf(w3, h2f((unsigned short)v3[j]), acc[j]);
                }
            }
            for (; s < dg16; s++) {
                int c = __shfl(my.x, s, 16);
                float w = __int_as_float(__shfl(my.y, s, 16));
                short8 v = *(const short8*)(hh + (size_t)c * D + lane * 8);
                #pragma unroll
                for (int j = 0; j < 8; j++) acc[j] = fmaf(w, h2f((unsigned short)v[j]), acc[j]);
            }
            for (s = 16; s < dg; s++) {              // astronomically rare tail
                int2 cw = ell2[n * ELL_CAP + s];
                float w = __int_as_float(cw.y);
                short8 v = *(const short8*)(hh + (size_t)cw.x * D + lane * 8);
                #pragma unroll
                for (int j = 0; j < 8; j++) acc[j] = fmaf(w, h2f((unsigned short)v[j]), acc[j]);
            }

            f32x4 a2, b2;
            {
                float h0 = h2f((unsigned short)hself[0]); float h1 = h2f((unsigned short)hself[1]);
                float h2 = h2f((unsigned short)hself[2]); float h3 = h2f((unsigned short)hself[3]);
                float h4 = h2f((unsigned short)hself[4]); float h5 = h2f((unsigned short)hself[5]);
                float h6 = h2f((unsigned short)hself[6]); float h7 = h2f((unsigned short)hself[7]);
                a2[0] = fmaf(h0, h0, acc[0]); a2[1] = fmaf(h1, h1, acc[1]);
                a2[2] = fmaf(h2, h2, acc[2]); a2[3] = fmaf(h3, h3, acc[3]);
                b2[0] = fmaf(h4, h4, acc[4]); b2[1] = fmaf(h5, h5, acc[5]);
                b2[2] = fmaf(h6, h6, acc[6]); b2[3] = fmaf(h7, h7, acc[7]);
            }
            float* o = out + (size_t)n * D + lane * 8;
            __builtin_nontemporal_store(a2, (f32x4*)o);
            __builtin_nontemporal_store(b2, (f32x4*)(o + 4));
        }
    }
}

// ================= R8-proven multi-kernel fallback (if cooperative launch fails) =================
__global__ __launch_bounds__(256) void fused_pre_kernel(const float* __restrict__ x,
                                                        float* __restrict__ stats,
                                                        const int* __restrict__ ei,
                                                        const float* __restrict__ ew,
                                                        int* __restrict__ deg,
                                                        int2* __restrict__ ell2,
                                                        const float* __restrict__ W,
                                                        unsigned short* __restrict__ Wb) {
    int b = blockIdx.x;
    int t = threadIdx.x;
    if (b < CS_BLOCKS) {
        int tid = b * 256 + t;
        const int NTH = CS_BLOCKS * 256;
        const float4* x4 = (const float4*)x;
        float4 v[CS_ITER];
        #pragma unroll
        for (int i = 0; i < CS_ITER; i++) v[i] = x4[tid + i * NTH];
        float4 s = {0.f, 0.f, 0.f, 0.f};
        float4 q = {0.f, 0.f, 0.f, 0.f};
        #pragma unroll
        for (int i = 0; i < CS_ITER; i++) {
            s.x += v[i].x; s.y += v[i].y; s.z += v[i].z; s.w += v[i].w;
            q.x += v[i].x * v[i].x; q.y += v[i].y * v[i].y;
            q.z += v[i].z * v[i].z; q.w += v[i].w * v[i].w;
        }
        __shared__ float4 ss[256];
        __shared__ float4 sq[256];
        ss[t] = s;
        sq[t] = q;
        __syncthreads();
        if (t < 32) {
            float4 a = ss[t];
            float4 bb = sq[t];
            for (int i = 32; i < 256; i += 32) {
                float4 t1 = ss[t + i];
                float4 t2 = sq[t + i];
                a.x += t1.x; a.y += t1.y; a.z += t1.z; a.w += t1.w;
                bb.x += t2.x; bb.y += t2.y; bb.z += t2.z; bb.w += t2.w;
            }
            float* st = stats + (b % NSTAT) * 256;
            int colb = (t * 4) & 127;
            atomicAdd(&st[colb + 0], a.x);
            atomicAdd(&st[colb + 1], a.y);
            atomicAdd(&st[colb + 2], a.z);
            atomicAdd(&st[colb + 3], a.w);
            atomicAdd(&st[128 + colb + 0], bb.x);
            atomicAdd(&st[128 + colb + 1], bb.y);
            atomicAdd(&st[128 + colb + 2], bb.z);
            atomicAdd(&st[128 + colb + 3], bb.w);
        }
    } else if (b < CS_BLOCKS + FILL_BLOCKS) {
        int e = (b - CS_BLOCKS) * 256 + t;
        if (e >= N_EDGES) return;
        int r = ei[e];
        int c = ei[N_EDGES + e];
        float w = ew[e];
        int slot = atomicAdd(&deg[r], 1);
        if (slot < ELL_CAP) ell2[r * ELL_CAP + slot] = make_int2(c, __float_as_int(w));
    } else {
        int i = (b - CS_BLOCKS - FILL_BLOCKS) * 256 + t;
        float4 v = *(const float4*)(W + i * 4);
        ushort4 o;
        o.x = f2bf(v.x); o.y = f2bf(v.y); o.z = f2bf(v.z); o.w = f2bf(v.w);
        *(ushort4*)(Wb + i * 4) = o;
    }
}

__global__ __launch_bounds__(256, 4) void gemm_mfma6_kernel(const float* __restrict__ x,
                                                            const float* __restrict__ stats,
                                                            const float* __restrict__ gamma,
                                                            const float* __restrict__ beta,
                                                            const unsigned short* __restrict__ Wb,
                                                            unsigned short* __restrict__ hh) {
    __shared__ __align__(16) unsigned short Yl[64 * YPAD];
    __shared__ float sscale[128];
    __shared__ float sshift[128];
    int t = threadIdx.x;
    int row0 = blockIdx.x * 64;
    int lane = t & 63;
    int wave = t >> 6;
    int m16  = lane & 15;
    int quad = lane >> 4;
    int wrow0 = wave * 16;
    int c4 = (t & 31) * 4;

    float4 xv[8];
    #pragma unroll
    for (int p = 0; p < 8; p++) {
        int r = (t + p * 256) >> 5;
        int grow = row0 + r;
        int srow = grow < N_NODES ? grow : N_NODES - 1;
        xv[p] = *(const float4*)(x + (size_t)srow * D + c4);
    }
    if (t < 128) {
        float sum = 0.f, sq = 0.f;
        #pragma unroll 16
        for (int c = 0; c < NSTAT; c++) {
            sum += stats[c * 256 + t];
            sq  += stats[c * 256 + 128 + t];
        }
        float mu  = sum * (1.0f / N_NODES);
        float var = sq * (1.0f / N_NODES) - mu * mu;
        float sc  = gamma[t] * rsqrtf(var + BN_EPS);
        sscale[t] = sc;
        sshift[t] = beta[t] - mu * sc;
    }
    __syncthreads();

    float4 sc = *(const float4*)(sscale + c4);
    float4 sh = *(const float4*)(sshift + c4);
    #pragma unroll
    for (int p = 0; p < 8; p++) {
        int r = (t + p * 256) >> 5;
        ushort4 y;
        y.x = f2bf(fmaxf(fmaf(xv[p].x, sc.x, sh.x), 0.f));
        y.y = f2bf(fmaxf(fmaf(xv[p].y, sc.y, sh.y), 0.f));
        y.z = f2bf(fmaxf(fmaf(xv[p].z, sc.z, sh.z), 0.f));
        y.w = f2bf(fmaxf(fmaf(xv[p].w, sc.w, sh.w), 0.f));
        *(ushort4*)(Yl + r * YPAD + c4) = y;
    }
    __syncthreads();

    f32x4 acc[8];
    #pragma unroll
    for (int nt = 0; nt < 8; nt++) acc[nt] = (f32x4){0.f, 0.f, 0.f, 0.f};

    const unsigned short* wb = Wb + m16 * D + quad * 8;
    const unsigned short* yl = Yl + (wrow0 + m16) * YPAD + quad * 8;
    #pragma unroll
    for (int kc = 0; kc < 4; kc++) {
        short8 a = *(const short8*)(yl + kc * 32);
        #pragma unroll
        for (int nt = 0; nt < 8; nt++) {
            short8 b = *(const short8*)(wb + nt * 16 * D + kc * 32);
            acc[nt] = __builtin_amdgcn_mfma_f32_16x16x32_bf16(a, b, acc[nt], 0, 0, 0);
        }
    }
    #pragma unroll
    for (int r = 0; r < 4; r++) {
        int grow = row0 + wrow0 + quad * 4 + r;
        if (grow < N_NODES) {
            unsigned short* hrow = hh + (size_t)grow * D + m16;
            #pragma unroll
            for (int nt = 0; nt < 8; nt++) {
                hrow[nt * 16] = f2h(acc[nt][r]);
            }
        }
    }
}

__global__ __launch_bounds__(256) void gather_ell6_kernel(const int* __restrict__ deg,
                                                          const int2* __restrict__ ell2,
                                                          const unsigned short* __restrict__ hh,
                                                          float* __restrict__ out) {
    int lane = threadIdx.x & 15;
    int n = blockIdx.x * 16 + (threadIdx.x >> 4);
    if (n >= N_NODES) return;
    short8 hself = *(const short8*)(hh + (size_t)n * D + lane * 8);
    int dg = __builtin_nontemporal_load(&deg[n]);
    if (dg > ELL_CAP) dg = ELL_CAP;
    int dg16 = dg < 16 ? dg : 16;

    int2 my = make_int2(0, 0);
    if (lane < dg16) my = ell2[n * ELL_CAP + lane];

    float acc[8] = {0.f, 0.f, 0.f, 0.f, 0.f, 0.f, 0.f, 0.f};
    int s = 0;
    for (; s + 4 <= dg16; s += 4) {
        int   c0 = __shfl(my.x, s + 0, 16); float w0 = __int_as_float(__shfl(my.y, s + 0, 16));
        int   c1 = __shfl(my.x, s + 1, 16); float w1 = __int_as_float(__shfl(my.y, s + 1, 16));
        int   c2 = __shfl(my.x, s + 2, 16); float w2 = __int_as_float(__shfl(my.y, s + 2, 16));
        int   c3 = __shfl(my.x, s + 3, 16); float w3 = __int_as_float(__shfl(my.y, s + 3, 16));
        short8 v0 = *(const short8*)(hh + (size_t)c0 * D + lane * 8);
        short8 v1 = *(const short8*)(hh + (size_t)c1 * D + lane * 8);
        short8 v2 = *(const short8*)(hh + (size_t)c2 * D + lane * 8);
        short8 v3 = *(const short8*)(hh + (size_t)c3 * D + lane * 8);
        #pragma unroll
        for (int j = 0; j < 8; j++) {
            acc[j] = fmaf(w0, h2f((unsigned short)v0[j]), acc[j]);
            acc[j] = fmaf(w1, h2f((unsigned short)v1[j]), acc[j]);
            acc[j] = fmaf(w2, h2f((unsigned short)v2[j]), acc[j]);
            acc[j] = fmaf(w3, h2f((unsigned short)v3[j]), acc[j]);
        }
    }
    for (; s < dg16; s++) {
        int c = __shfl(my.x, s, 16);
        float w = __int_as_float(__shfl(my.y, s, 16));
        short8 v = *(const short8*)(hh + (size_t)c * D + lane * 8);
        #pragma unroll
        for (int j = 0; j < 8; j++) acc[j] = fmaf(w, h2f((unsigned short)v[j]), acc[j]);
    }
    for (s = 16; s < dg; s++) {
        int2 cw = ell2[n * ELL_CAP + s];
        float w = __int_as_float(cw.y);
        short8 v = *(const short8*)(hh + (size_t)cw.x * D + lane * 8);
        #pragma unroll
        for (int j = 0; j < 8; j++) acc[j] = fmaf(w, h2f((unsigned short)v[j]), acc[j]);
    }

    f32x4 a, b;
    {
        float h0 = h2f((unsigned short)hself[0]); float h1 = h2f((unsigned short)hself[1]);
        float h2 = h2f((unsigned short)hself[2]); float h3 = h2f((unsigned short)hself[3]);
        float h4 = h2f((unsigned short)hself[4]); float h5 = h2f((unsigned short)hself[5]);
        float h6 = h2f((unsigned short)hself[6]); float h7 = h2f((unsigned short)hself[7]);
        a[0] = fmaf(h0, h0, acc[0]); a[1] = fmaf(h1, h1, acc[1]);
        a[2] = fmaf(h2, h2, acc[2]); a[3] = fmaf(h3, h3, acc[3]);
        b[0] = fmaf(h4, h4, acc[4]); b[1] = fmaf(h5, h5, acc[5]);
        b[2] = fmaf(h6, h6, acc[6]); b[3] = fmaf(h7, h7, acc[7]);
    }
    float* o = out + (size_t)n * D + lane * 8;
    __builtin_nontemporal_store(a, (f32x4*)o);
    __builtin_nontemporal_store(b, (f32x4*)(o + 4));
}

// ================= CSR fallback path (proven, R3) =================
__global__ __launch_bounds__(256) void colstats_kernel(const float* __restrict__ x,
                                                       float* __restrict__ stats,
                                                       int* __restrict__ deg) {
    int tid = blockIdx.x * 256 + threadIdx.x;
    if (deg && tid < N_NODES) deg[tid] = 0;
    const int NTH = CS_BLOCKS * 256;
    const float4* x4 = (const float4*)x;
    float4 v[CS_ITER];
    #pragma unroll
    for (int i = 0; i < CS_ITER; i++) v[i] = x4[tid + i * NTH];
    float4 s = {0.f, 0.f, 0.f, 0.f};
    float4 q = {0.f, 0.f, 0.f, 0.f};
    #pragma unroll
    for (int i = 0; i < CS_ITER; i++) {
        s.x += v[i].x; s.y += v[i].y; s.z += v[i].z; s.w += v[i].w;
        q.x += v[i].x * v[i].x; q.y += v[i].y * v[i].y;
        q.z += v[i].z * v[i].z; q.w += v[i].w * v[i].w;
    }
    __shared__ float4 ss[256];
    __shared__ float4 sq[256];
    ss[threadIdx.x] = s;
    sq[threadIdx.x] = q;
    __syncthreads();
    if (threadIdx.x < 32) {
        float4 a = ss[threadIdx.x];
        float4 b = sq[threadIdx.x];
        for (int i = 32; i < 256; i += 32) {
            float4 t1 = ss[threadIdx.x + i];
            float4 t2 = sq[threadIdx.x + i];
            a.x += t1.x; a.y += t1.y; a.z += t1.z; a.w += t1.w;
            b.x += t2.x; b.y += t2.y; b.z += t2.z; b.w += t2.w;
        }
        float* st = stats + (blockIdx.x % NSTAT) * 256;
        int colb = (threadIdx.x * 4) & 127;
        atomicAdd(&st[colb + 0], a.x);
        atomicAdd(&st[colb + 1], a.y);
        atomicAdd(&st[colb + 2], a.z);
        atomicAdd(&st[colb + 3], a.w);
        atomicAdd(&st[128 + colb + 0], b.x);
        atomicAdd(&st[128 + colb + 1], b.y);
        atomicAdd(&st[128 + colb + 2], b.z);
        atomicAdd(&st[128 + colb + 3], b.w);
    }
}

__global__ __launch_bounds__(128) void finalize_kernel(const float* __restrict__ stats,
                                                       const float* __restrict__ gamma,
                                                       const float* __restrict__ beta,
                                                       float* __restrict__ scale,
                                                       float* __restrict__ shift) {
    int d = threadIdx.x;
    float sum = 0.f, sq = 0.f;
    #pragma unroll 16
    for (int c = 0; c < NSTAT; c++) {
        sum += stats[c * 256 + d];
        sq  += stats[c * 256 + 128 + d];
    }
    float mu  = sum * (1.0f / N_NODES);
    float var = sq * (1.0f / N_NODES) - mu * mu;
    float sc  = gamma[d] * rsqrtf(var + BN_EPS);
    scale[d] = sc;
    shift[d] = beta[d] - mu * sc;
}

__global__ __launch_bounds__(256) void transposeW_kernel(const float* __restrict__ W,
                                                         float* __restrict__ Wt) {
    int i = blockIdx.x * blockDim.x + threadIdx.x;
    if (i < D * D) {
        int j = i >> 7;
        int k = i & 127;
        Wt[k * D + j] = W[i];
    }
}

template <int WRITE_SQ>
__global__ __launch_bounds__(256) void gemm_kernel(const float* __restrict__ x,
                                                   const float* __restrict__ scale,
                                                   const float* __restrict__ shift,
                                                   const float* __restrict__ Wt,
                                                   float* __restrict__ h,
                                                   float* __restrict__ out) {
    __shared__ float Ws[D * D];
    __shared__ float Ys[32 * D];
    int t = threadIdx.x;
    const float4* Wt4 = (const float4*)Wt;
    float4* Ws4 = (float4*)Ws;
    #pragma unroll 4
    for (int i = t; i < D * D / 4; i += 256) Ws4[i] = Wt4[i];
    int row0 = blockIdx.x * 32;
    const float4* x4 = (const float4*)(x + (size_t)row0 * D);
    float4* Ys4 = (float4*)Ys;
    #pragma unroll 2
    for (int i = t; i < 32 * D / 4; i += 256) {
        int c4 = (i & 31) * 4;
        float4 v = x4[i];
        v.x = fmaxf(fmaf(v.x, scale[c4 + 0], shift[c4 + 0]), 0.f);
        v.y = fmaxf(fmaf(v.y, scale[c4 + 1], shift[c4 + 1]), 0.f);
        v.z = fmaxf(fmaf(v.z, scale[c4 + 2], shift[c4 + 2]), 0.f);
        v.w = fmaxf(fmaf(v.w, scale[c4 + 3], shift[c4 + 3]), 0.f);
        Ys4[i] = v;
    }
    __syncthreads();
    int cg2 = t & 31;
    int rg = t >> 5;
    float4 acc[4] = {{0,0,0,0},{0,0,0,0},{0,0,0,0},{0,0,0,0}};
    #pragma unroll 2
    for (int k = 0; k < D; k += 4) {
        float4 w0 = *(const float4*)&Ws[(k + 0) * D + cg2 * 4];
        float4 w1 = *(const float4*)&Ws[(k + 1) * D + cg2 * 4];
        float4 w2 = *(const float4*)&Ws[(k + 2) * D + cg2 * 4];
        float4 w3 = *(const float4*)&Ws[(k + 3) * D + cg2 * 4];
        #pragma unroll
        for (int r = 0; r < 4; r++) {
            float4 y = *(const float4*)&Ys[(rg * 4 + r) * D + k];
            acc[r].x = fmaf(y.x, w0.x, fmaf(y.y, w1.x, fmaf(y.z, w2.x, fmaf(y.w, w3.x, acc[r].x))));
            acc[r].y = fmaf(y.x, w0.y, fmaf(y.y, w1.y, fmaf(y.z, w2.y, fmaf(y.w, w3.y, acc[r].y))));
            acc[r].z = fmaf(y.x, w0.z, fmaf(y.y, w1.z, fmaf(y.z, w2.z, fmaf(y.w, w3.z, acc[r].z))));
            acc[r].w = fmaf(y.x, w0.w, fmaf(y.y, w1.w, fmaf(y.z, w2.w, fmaf(y.w, w3.w, acc[r].w))));
        }
    }
    #pragma unroll
    for (int r = 0; r < 4; r++) {
        size_t row = (size_t)row0 + rg * 4 + r;
        float4 v = acc[r];
        *(float4*)&h[row * D + cg2 * 4] = v;
        if (WRITE_SQ) {
            float4 sqv = {v.x * v.x, v.y * v.y, v.z * v.z, v.w * v.w};
            *(float4*)&out[row * D + cg2 * 4] = sqv;
        }
    }
}

__global__ __launch_bounds__(256) void hist_kernel(const int* __restrict__ ei,
                                                   int* __restrict__ deg) {
    int e = blockIdx.x * 256 + threadIdx.x;
    if (e < N_EDGES) atomicAdd(&deg[ei[e]], 1);
}

__global__ __launch_bounds__(1024) void scan_kernel(const int* __restrict__ deg,
                                                    int* __restrict__ row_ptr,
                                                    int* __restrict__ cursor) {
    __shared__ int part[1024];
    int t = threadIdx.x;
    const int CHUNK = 100;
    int base = t * CHUNK;
    int s = 0;
    if (base < N_NODES) {
        for (int i = 0; i < CHUNK; i++) s += deg[base + i];
    }
    part[t] = s;
    __syncthreads();
    for (int off = 1; off < 1024; off <<= 1) {
        int v = (t >= off) ? part[t - off] : 0;
        __syncthreads();
        part[t] += v;
        __syncthreads();
    }
    int pre = (t == 0) ? 0 : part[t - 1];
    if (base < N_NODES) {
        for (int i = 0; i < CHUNK; i++) {
            row_ptr[base + i] = pre;
            cursor[base + i] = pre;
            pre += deg[base + i];
        }
    }
    if (t == 1023) row_ptr[N_NODES] = part[1023];
}

__global__ __launch_bounds__(256) void fill_kernel(const int* __restrict__ ei,
                                                   const float* __restrict__ ew,
                                                   int* __restrict__ cursor,
                                                   int* __restrict__ csr_col,
                                                   float* __restrict__ csr_w) {
    int e = blockIdx.x * 256 + threadIdx.x;
    if (e >= N_EDGES) return;
    int r = ei[e];
    int c = ei[N_EDGES + e];
    int slot = atomicAdd(&cursor[r], 1);
    csr_col[slot] = c;
    csr_w[slot] = ew[e];
}

__global__ __launch_bounds__(256) void gather_kernel(const int* __restrict__ row_ptr,
                                                     const int* __restrict__ csr_col,
                                                     const float* __restrict__ csr_w,
                                                     const float* __restrict__ h,
                                                     float* __restrict__ out) {
    int lane = threadIdx.x & 31;
    int n = blockIdx.x * 8 + (threadIdx.x >> 5);
    if (n >= N_NODES) return;
    int s0 = row_ptr[n];
    int s1 = row_ptr[n + 1];
    float4 acc = {0.f, 0.f, 0.f, 0.f};
    for (int s = s0; s < s1; s++) {
        int c = csr_col[s];
        float w = csr_w[s];
        float4 v = *(const float4*)&h[(size_t)c * D + lane * 4];
        acc.x = fmaf(w, v.x, acc.x);
        acc.y = fmaf(w, v.y, acc.y);
        acc.z = fmaf(w, v.z, acc.z);
        acc.w = fmaf(w, v.w, acc.w);
    }
    float4 hv = *(const float4*)&h[(size_t)n * D + lane * 4];
    float4 o;
    o.x = fmaf(hv.x, hv.x, acc.x);
    o.y = fmaf(hv.y, hv.y, acc.y);
    o.z = fmaf(hv.z, hv.z, acc.z);
    o.w = fmaf(hv.w, hv.w, acc.w);
    *(float4*)&out[(size_t)n * D + lane * 4] = o;
}

__global__ __launch_bounds__(256) void scatter_kernel(const int* __restrict__ ei,
                                                      const float* __restrict__ ew,
                                                      const float* __restrict__ h,
                                                      float* __restrict__ out) {
    int lane = threadIdx.x & 31;
    int e = blockIdx.x * 8 + (threadIdx.x >> 5);
    if (e >= N_EDGES) return;
    int r = ei[e];
    int c = ei[N_EDGES + e];
    float w = ew[e];
    float4 v = *(const float4*)&h[(size_t)c * D + lane * 4];
    float* o = out + (size_t)r * D + lane * 4;
    atomicAdd(o + 0, v.x * w);
    atomicAdd(o + 1, v.y * w);
    atomicAdd(o + 2, v.z * w);
    atomicAdd(o + 3, v.w * w);
}

extern "C" void kernel_launch(void* const* d_in, const int* in_sizes, int n_in,
                              void* d_out, int out_size, void* d_ws, size_t ws_size,
                              hipStream_t stream) {
    const float* n_feat = (const float*)d_in[0];
    const int*   ei     = (const int*)d_in[1];
    const float* ew     = (const float*)d_in[2];
    const float* gamma  = (const float*)d_in[3];
    const float* beta   = (const float*)d_in[4];
    const float* W      = (const float*)d_in[5];
    float* out = (float*)d_out;

    float* ws    = (float*)d_ws;
    float* stats = ws + WS_STATS;

    bool ell_ok = ws_size >= (size_t)WS_ELL_END2 * sizeof(float);
    bool csr_ok = ws_size >= (size_t)WS_END * sizeof(float);

    if (ell_ok) {
        unsigned short* hh  = (unsigned short*)(ws + WS_HB);
        int*  deg  = (int*)ws + WS_DEG2;
        int2* ell2 = (int2*)((int*)ws + WS_ELL2);
        unsigned short* Wb = (unsigned short*)(ws + WS_WB);

        // ---- try the 1-dispatch cooperative mega-kernel ----
        void* args[] = {
            (void*)&n_feat, (void*)&stats, (void*)&ei, (void*)&ew,
            (void*)&deg, (void*)&ell2, (void*)&W, (void*)&Wb,
            (void*)&gamma, (void*)&beta, (void*)&hh, (void*)&out
        };
        hipError_t err = hipLaunchCooperativeKernel((const void*)mega_kernel,
                                                    dim3(MEGA_BLOCKS), dim3(256),
                                                    args, 0, stream);
        if (err != hipSuccess) {
            // ---- R8-proven multi-kernel fallback ----
            (void)hipMemsetAsync(stats, 0, NSTAT * 256 * sizeof(float), stream);
            (void)hipMemsetAsync(deg, 0, N_NODES * sizeof(int), stream);
            fused_pre_kernel<<<CS_BLOCKS + FILL_BLOCKS + 16, 256, 0, stream>>>(
                n_feat, stats, ei, ew, deg, ell2, W, Wb);
            gemm_mfma6_kernel<<<(N_NODES + 63) / 64, 256, 0, stream>>>(n_feat, stats, gamma, beta, Wb, hh);
            gather_ell6_kernel<<<(N_NODES + 15) / 16, 256, 0, stream>>>(deg, ell2, hh, out);
        }
    } else if (csr_ok) {
        float* scale = ws + WS_SCALE;
        float* shift = ws + WS_SHIFT;
        float* Wt    = ws + WS_WT;
        float* h     = ws + WS_H;
        int*   deg     = (int*)ws + WS_DEG;
        int*   row_ptr = (int*)ws + WS_ROWPTR;
        int*   cursor  = (int*)ws + WS_CURSOR;
        int*   csr_col = (int*)ws + WS_CSRCOL;
        float* csr_w   = ws + WS_CSRW;

        (void)hipMemsetAsync(stats, 0, NSTAT * 256 * sizeof(float), stream);
        colstats_kernel<<<CS_BLOCKS, 256, 0, stream>>>(n_feat, stats, nullptr);
        finalize_kernel<<<1, 128, 0, stream>>>(stats, gamma, beta, scale, shift);
        transposeW_kernel<<<64, 256, 0, stream>>>(W, Wt);
        (void)hipMemsetAsync(deg, 0, N_NODES * sizeof(int), stream);
        gemm_kernel<0><<<N_NODES / 32, 256, 0, stream>>>(n_feat, scale, shift, Wt, h, out);
        hist_kernel<<<(N_EDGES + 255) / 256, 256, 0, stream>>>(ei, deg);
        scan_kernel<<<1, 1024, 0, stream>>>(deg, row_ptr, cursor);
        fill_kernel<<<(N_EDGES + 255) / 256, 256, 0, stream>>>(ei, ew, cursor, csr_col, csr_w);
        gather_kernel<<<(N_NODES + 7) / 8, 256, 0, stream>>>(row_ptr, csr_col, csr_w, h, out);
    } else {
        float* scale = ws + WS_SCALE;
        float* shift = ws + WS_SHIFT;
        float* Wt    = ws + WS_WT;
        float* h     = ws + WS_H;
        (void)hipMemsetAsync(stats, 0, NSTAT * 256 * sizeof(float), stream);
        colstats_kernel<<<CS_BLOCKS, 256, 0, stream>>>(n_feat, stats, nullptr);
        finalize_kernel<<<1, 128, 0, stream>>>(stats, gamma, beta, scale, shift);
        transposeW_kernel<<<64, 256, 0, stream>>>(W, Wt);
        gemm_kernel<1><<<N_NODES / 32, 256, 0, stream>>>(n_feat, scale, shift, Wt, h, out);
        scatter_kernel<<<(N_EDGES + 7) / 8, 256, 0, stream>>>(ei, ew, h, out);
    }
}

// Round 10
// 194.503 us; speedup vs baseline: 2.5185x; 2.5185x over previous
//
#include <hip/hip_runtime.h>

#define N_NODES 100000
#define N_EDGES 400000
#define D 128
#define BN_EPS 1e-5f
#define ELL_CAP 32

#define NSTAT 64                                     // striped stat copies (atomic decongestion)
#define CS_BLOCKS 625                                // 625*256 = 160000 threads
#define CS_ITER 20                                   // 3.2M float4 / 160k = exactly 20/thread
#define FILL_BLOCKS 1563                             // ceil(400000/256)

// ===== primary (ELL2/fp16-h) ws layout, 4B units =====
#define WS_STATS   0                                 // NSTAT*256 floats (64KB)
#define WS_HB      (NSTAT * 256)                     // N*D fp16 = 6.4M float slots
#define WS_DEG2    (WS_HB + N_NODES * D / 2)         // 100000 ints
#define WS_ELL2    (WS_DEG2 + N_NODES)               // N*ELL_CAP int2 = 6.4M ints
#define WS_ELL2_END (WS_ELL2 + N_NODES * ELL_CAP * 2)
#define WS_WB      WS_ELL2_END                       // W as bf16: 16384 ushort = 8192 slots
#define WS_ELL_END2 (WS_WB + 8192)
// ===== CSR fallback layout (proven R3) =====
#define WS_SCALE   (NSTAT * 256)
#define WS_SHIFT   (WS_SCALE + 128)
#define WS_WT      (WS_SHIFT + 128)
#define WS_H       (WS_WT + D * D)
#define WS_DEG     (WS_H + N_NODES * D)
#define WS_ROWPTR  (WS_DEG + N_NODES)
#define WS_CURSOR  (WS_ROWPTR + N_NODES + 1)
#define WS_CSRCOL  (WS_CURSOR + N_NODES)
#define WS_CSRW    (WS_CSRCOL + N_EDGES)
#define WS_END     (WS_CSRW + N_EDGES)

typedef __attribute__((ext_vector_type(8))) short short8;
typedef __attribute__((ext_vector_type(4))) float f32x4;

static __device__ __forceinline__ unsigned short f2bf(float f) {
    union { float f; unsigned u; } v; v.f = f;
    unsigned r = v.u + 0x7FFF + ((v.u >> 16) & 1);   // RNE
    return (unsigned short)(r >> 16);
}
static __device__ __forceinline__ float bf2f(unsigned short b) {
    union { unsigned u; float f; } v; v.u = ((unsigned)b) << 16;
    return v.f;
}
static __device__ __forceinline__ unsigned short f2h(float f) {
    union { _Float16 h; unsigned short u; } v; v.h = (_Float16)f;   // v_cvt_f16_f32, RNE
    return v.u;
}
static __device__ __forceinline__ float h2f(unsigned short u) {
    union { unsigned short u; _Float16 h; } v; v.u = u;
    return (float)v.h;
}

// ---------------- fused pre-stage: colstats || ell2-fill || convW ----------------
// R10: sched_barrier(0) between the 20 loads and the accumulate loop. R2's profile showed
// VGPR_Count=12 for colstats -> the compiler had collapsed the intended 20-deep MLP into a
// 2-buffer load->add chain. The fence forces all 20 loads in flight (true MLP, ~100 VGPR).
__global__ __launch_bounds__(256) void fused_pre_kernel(const float* __restrict__ x,
                                                        float* __restrict__ stats,
                                                        const int* __restrict__ ei,
                                                        const float* __restrict__ ew,
                                                        int* __restrict__ deg,
                                                        int2* __restrict__ ell2,
                                                        const float* __restrict__ W,
                                                        unsigned short* __restrict__ Wb) {
    int b = blockIdx.x;
    int t = threadIdx.x;
    if (b < CS_BLOCKS) {
        int tid = b * 256 + t;
        const int NTH = CS_BLOCKS * 256;             // 160000
        const float4* x4 = (const float4*)x;
        float4 v[CS_ITER];
        #pragma unroll
        for (int i = 0; i < CS_ITER; i++) v[i] = x4[tid + i * NTH];
        __builtin_amdgcn_sched_barrier(0);           // all 20 loads issued before any math
        float4 s = {0.f, 0.f, 0.f, 0.f};
        float4 q = {0.f, 0.f, 0.f, 0.f};
        #pragma unroll
        for (int i = 0; i < CS_ITER; i++) {
            s.x += v[i].x; s.y += v[i].y; s.z += v[i].z; s.w += v[i].w;
            q.x += v[i].x * v[i].x; q.y += v[i].y * v[i].y;
            q.z += v[i].z * v[i].z; q.w += v[i].w * v[i].w;
        }
        __shared__ float4 ss[256];
        __shared__ float4 sq[256];
        ss[t] = s;
        sq[t] = q;
        __syncthreads();
        if (t < 32) {
            float4 a = ss[t];
            float4 bb = sq[t];
            for (int i = 32; i < 256; i += 32) {
                float4 t1 = ss[t + i];
                float4 t2 = sq[t + i];
                a.x += t1.x; a.y += t1.y; a.z += t1.z; a.w += t1.w;
                bb.x += t2.x; bb.y += t2.y; bb.z += t2.z; bb.w += t2.w;
            }
            float* st = stats + (b % NSTAT) * 256;   // striped copy
            int colb = (t * 4) & 127;
            atomicAdd(&st[colb + 0], a.x);
            atomicAdd(&st[colb + 1], a.y);
            atomicAdd(&st[colb + 2], a.z);
            atomicAdd(&st[colb + 3], a.w);
            atomicAdd(&st[128 + colb + 0], bb.x);
            atomicAdd(&st[128 + colb + 1], bb.y);
            atomicAdd(&st[128 + colb + 2], bb.z);
            atomicAdd(&st[128 + colb + 3], bb.w);
        }
    } else if (b < CS_BLOCKS + FILL_BLOCKS) {
        int e = (b - CS_BLOCKS) * 256 + t;
        if (e >= N_EDGES) return;
        int r = ei[e];
        int c = ei[N_EDGES + e];
        float w = ew[e];
        int slot = atomicAdd(&deg[r], 1);
        if (slot < ELL_CAP) ell2[r * ELL_CAP + slot] = make_int2(c, __float_as_int(w));
    } else {
        int i = (b - CS_BLOCKS - FILL_BLOCKS) * 256 + t;
        float4 v = *(const float4*)(W + i * 4);
        ushort4 o;
        o.x = f2bf(v.x); o.y = f2bf(v.y); o.z = f2bf(v.z); o.w = f2bf(v.w);
        *(ushort4*)(Wb + i * 4) = o;
    }
}

// ---------------- MFMA gemm v7: per-kc B-frag batch preload (8 independent loads) ----------------
// R3-R8 invariant 42us explained: 32 serialized {Wb-load -> MFMA} dependent pairs = 32 x ~200cy
// L2 latency per block, x 6.1 blocks/CU / 2.5 concurrent. Now latency is paid once per kc:
// 8 independent loads (32 VGPR) -> fence -> 8 MFMAs. Total VGPR ~110, fits (256,4).
#define YPAD 136
__global__ __launch_bounds__(256, 4) void gemm_mfma7_kernel(const float* __restrict__ x,
                                                            const float* __restrict__ stats,
                                                            const float* __restrict__ gamma,
                                                            const float* __restrict__ beta,
                                                            const unsigned short* __restrict__ Wb,
                                                            unsigned short* __restrict__ hh) {
    __shared__ __align__(16) unsigned short Yl[64 * YPAD];
    __shared__ float sscale[128];
    __shared__ float sshift[128];
    int t = threadIdx.x;
    int row0 = blockIdx.x * 64;
    int lane = t & 63;
    int wave = t >> 6;
    int m16  = lane & 15;
    int quad = lane >> 4;
    int wrow0 = wave * 16;
    int c4 = (t & 31) * 4;

    // issue 8 independent x row-loads first
    float4 xv[8];
    #pragma unroll
    for (int p = 0; p < 8; p++) {
        int r = (t + p * 256) >> 5;
        int grow = row0 + r;
        int srow = grow < N_NODES ? grow : N_NODES - 1;
        xv[p] = *(const float4*)(x + (size_t)srow * D + c4);
    }
    __builtin_amdgcn_sched_barrier(0);               // keep all 8 x-loads in flight
    // fused finalize: sum 64 L2-resident stripes -> scale/shift in LDS
    if (t < 128) {
        float sum = 0.f, sq = 0.f;
        #pragma unroll 16
        for (int c = 0; c < NSTAT; c++) {
            sum += stats[c * 256 + t];
            sq  += stats[c * 256 + 128 + t];
        }
        float mu  = sum * (1.0f / N_NODES);
        float var = sq * (1.0f / N_NODES) - mu * mu;
        float sc  = gamma[t] * rsqrtf(var + BN_EPS);
        sscale[t] = sc;
        sshift[t] = beta[t] - mu * sc;
    }
    __syncthreads();

    float4 sc = *(const float4*)(sscale + c4);
    float4 sh = *(const float4*)(sshift + c4);
    #pragma unroll
    for (int p = 0; p < 8; p++) {
        int r = (t + p * 256) >> 5;
        ushort4 y;
        y.x = f2bf(fmaxf(fmaf(xv[p].x, sc.x, sh.x), 0.f));
        y.y = f2bf(fmaxf(fmaf(xv[p].y, sc.y, sh.y), 0.f));
        y.z = f2bf(fmaxf(fmaf(xv[p].z, sc.z, sh.z), 0.f));
        y.w = f2bf(fmaxf(fmaf(xv[p].w, sc.w, sh.w), 0.f));
        *(ushort4*)(Yl + r * YPAD + c4) = y;
    }
    __syncthreads();

    f32x4 acc[8];
    #pragma unroll
    for (int nt = 0; nt < 8; nt++) acc[nt] = (f32x4){0.f, 0.f, 0.f, 0.f};

    const unsigned short* wb = Wb + m16 * D + quad * 8;            // B[k][n]=Wb[n][k]
    const unsigned short* yl = Yl + (wrow0 + m16) * YPAD + quad * 8;
    #pragma unroll
    for (int kc = 0; kc < 4; kc++) {
        short8 bfr[8];
        #pragma unroll
        for (int nt = 0; nt < 8; nt++) {
            bfr[nt] = *(const short8*)(wb + nt * 16 * D + kc * 32);
        }
        __builtin_amdgcn_sched_barrier(0);           // 8 B-loads in flight before MFMAs
        short8 a = *(const short8*)(yl + kc * 32);
        #pragma unroll
        for (int nt = 0; nt < 8; nt++) {
            acc[nt] = __builtin_amdgcn_mfma_f32_16x16x32_bf16(a, bfr[nt], acc[nt], 0, 0, 0);
        }
    }

    // epilogue: hh = fp16(h) only (C/D: col=lane&15, row=quad*4+reg)
    #pragma unroll
    for (int r = 0; r < 4; r++) {
        int grow = row0 + wrow0 + quad * 4 + r;
        if (grow < N_NODES) {
            unsigned short* hrow = hh + (size_t)grow * D + m16;
            #pragma unroll
            for (int nt = 0; nt < 8; nt++) {
                hrow[nt * 16] = f2h(acc[nt][r]);
            }
        }
    }
}

// ---------------- ELL2 gather v7: R5 structure + MLP fence + nt out stores ----------------
__global__ __launch_bounds__(256) void gather_ell7_kernel(const int* __restrict__ deg,
                                                          const int2* __restrict__ ell2,
                                                          const unsigned short* __restrict__ hh,
                                                          float* __restrict__ out) {
    int lane = threadIdx.x & 15;                 // 16 lanes per node
    int n = blockIdx.x * 16 + (threadIdx.x >> 4);
    if (n >= N_NODES) return;
    short8 hself = *(const short8*)(hh + (size_t)n * D + lane * 8);   // issue early
    int dg = __builtin_nontemporal_load(&deg[n]);
    if (dg > ELL_CAP) dg = ELL_CAP;
    int dg16 = dg < 16 ? dg : 16;

    int2 my = make_int2(0, 0);
    if (lane < dg16) my = ell2[n * ELL_CAP + lane];

    float acc[8] = {0.f, 0.f, 0.f, 0.f, 0.f, 0.f, 0.f, 0.f};
    int s = 0;
    for (; s + 4 <= dg16; s += 4) {
        int   c0 = __shfl(my.x, s + 0, 16); float w0 = __int_as_float(__shfl(my.y, s + 0, 16));
        int   c1 = __shfl(my.x, s + 1, 16); float w1 = __int_as_float(__shfl(my.y, s + 1, 16));
        int   c2 = __shfl(my.x, s + 2, 16); float w2 = __int_as_float(__shfl(my.y, s + 2, 16));
        int   c3 = __shfl(my.x, s + 3, 16); float w3 = __int_as_float(__shfl(my.y, s + 3, 16));
        short8 v0 = *(const short8*)(hh + (size_t)c0 * D + lane * 8);
        short8 v1 = *(const short8*)(hh + (size_t)c1 * D + lane * 8);
        short8 v2 = *(const short8*)(hh + (size_t)c2 * D + lane * 8);
        short8 v3 = *(const short8*)(hh + (size_t)c3 * D + lane * 8);
        __builtin_amdgcn_sched_barrier(0);       // 4 gathers in flight before FMAs
        #pragma unroll
        for (int j = 0; j < 8; j++) {
            acc[j] = fmaf(w0, h2f((unsigned short)v0[j]), acc[j]);
            acc[j] = fmaf(w1, h2f((unsigned short)v1[j]), acc[j]);
            acc[j] = fmaf(w2, h2f((unsigned short)v2[j]), acc[j]);
            acc[j] = fmaf(w3, h2f((unsigned short)v3[j]), acc[j]);
        }
    }
    for (; s < dg16; s++) {
        int c = __shfl(my.x, s, 16);
        float w = __int_as_float(__shfl(my.y, s, 16));
        short8 v = *(const short8*)(hh + (size_t)c * D + lane * 8);
        #pragma unroll
        for (int j = 0; j < 8; j++) acc[j] = fmaf(w, h2f((unsigned short)v[j]), acc[j]);
    }
    for (s = 16; s < dg; s++) {                  // astronomically rare tail (deg > 16)
        int2 cw = ell2[n * ELL_CAP + s];
        float w = __int_as_float(cw.y);
        short8 v = *(const short8*)(hh + (size_t)cw.x * D + lane * 8);
        #pragma unroll
        for (int j = 0; j < 8; j++) acc[j] = fmaf(w, h2f((unsigned short)v[j]), acc[j]);
    }

    f32x4 a, b;
    {
        float h0 = h2f((unsigned short)hself[0]); float h1 = h2f((unsigned short)hself[1]);
        float h2 = h2f((unsigned short)hself[2]); float h3 = h2f((unsigned short)hself[3]);
        float h4 = h2f((unsigned short)hself[4]); float h5 = h2f((unsigned short)hself[5]);
        float h6 = h2f((unsigned short)hself[6]); float h7 = h2f((unsigned short)hself[7]);
        a[0] = fmaf(h0, h0, acc[0]); a[1] = fmaf(h1, h1, acc[1]);
        a[2] = fmaf(h2, h2, acc[2]); a[3] = fmaf(h3, h3, acc[3]);
        b[0] = fmaf(h4, h4, acc[4]); b[1] = fmaf(h5, h5, acc[5]);
        b[2] = fmaf(h6, h6, acc[6]); b[3] = fmaf(h7, h7, acc[7]);
    }
    float* o = out + (size_t)n * D + lane * 8;
    __builtin_nontemporal_store(a, (f32x4*)o);
    __builtin_nontemporal_store(b, (f32x4*)(o + 4));
}

// ================= CSR fallback path (proven, R3) =================
__global__ __launch_bounds__(256) void colstats_kernel(const float* __restrict__ x,
                                                       float* __restrict__ stats,
                                                       int* __restrict__ deg) {
    int tid = blockIdx.x * 256 + threadIdx.x;
    if (deg && tid < N_NODES) deg[tid] = 0;
    const int NTH = CS_BLOCKS * 256;
    const float4* x4 = (const float4*)x;
    float4 v[CS_ITER];
    #pragma unroll
    for (int i = 0; i < CS_ITER; i++) v[i] = x4[tid + i * NTH];
    __builtin_amdgcn_sched_barrier(0);
    float4 s = {0.f, 0.f, 0.f, 0.f};
    float4 q = {0.f, 0.f, 0.f, 0.f};
    #pragma unroll
    for (int i = 0; i < CS_ITER; i++) {
        s.x += v[i].x; s.y += v[i].y; s.z += v[i].z; s.w += v[i].w;
        q.x += v[i].x * v[i].x; q.y += v[i].y * v[i].y;
        q.z += v[i].z * v[i].z; q.w += v[i].w * v[i].w;
    }
    __shared__ float4 ss[256];
    __shared__ float4 sq[256];
    ss[threadIdx.x] = s;
    sq[threadIdx.x] = q;
    __syncthreads();
    if (threadIdx.x < 32) {
        float4 a = ss[threadIdx.x];
        float4 b = sq[threadIdx.x];
        for (int i = 32; i < 256; i += 32) {
            float4 t1 = ss[threadIdx.x + i];
            float4 t2 = sq[threadIdx.x + i];
            a.x += t1.x; a.y += t1.y; a.z += t1.z; a.w += t1.w;
            b.x += t2.x; b.y += t2.y; b.z += t2.z; b.w += t2.w;
        }
        float* st = stats + (blockIdx.x % NSTAT) * 256;
        int colb = (threadIdx.x * 4) & 127;
        atomicAdd(&st[colb + 0], a.x);
        atomicAdd(&st[colb + 1], a.y);
        atomicAdd(&st[colb + 2], a.z);
        atomicAdd(&st[colb + 3], a.w);
        atomicAdd(&st[128 + colb + 0], b.x);
        atomicAdd(&st[128 + colb + 1], b.y);
        atomicAdd(&st[128 + colb + 2], b.z);
        atomicAdd(&st[128 + colb + 3], b.w);
    }
}

__global__ __launch_bounds__(128) void finalize_kernel(const float* __restrict__ stats,
                                                       const float* __restrict__ gamma,
                                                       const float* __restrict__ beta,
                                                       float* __restrict__ scale,
                                                       float* __restrict__ shift) {
    int d = threadIdx.x;
    float sum = 0.f, sq = 0.f;
    #pragma unroll 16
    for (int c = 0; c < NSTAT; c++) {
        sum += stats[c * 256 + d];
        sq  += stats[c * 256 + 128 + d];
    }
    float mu  = sum * (1.0f / N_NODES);
    float var = sq * (1.0f / N_NODES) - mu * mu;
    float sc  = gamma[d] * rsqrtf(var + BN_EPS);
    scale[d] = sc;
    shift[d] = beta[d] - mu * sc;
}

__global__ __launch_bounds__(256) void transposeW_kernel(const float* __restrict__ W,
                                                         float* __restrict__ Wt) {
    int i = blockIdx.x * blockDim.x + threadIdx.x;
    if (i < D * D) {
        int j = i >> 7;
        int k = i & 127;
        Wt[k * D + j] = W[i];
    }
}

template <int WRITE_SQ>
__global__ __launch_bounds__(256) void gemm_kernel(const float* __restrict__ x,
                                                   const float* __restrict__ scale,
                                                   const float* __restrict__ shift,
                                                   const float* __restrict__ Wt,
                                                   float* __restrict__ h,
                                                   float* __restrict__ out) {
    __shared__ float Ws[D * D];
    __shared__ float Ys[32 * D];
    int t = threadIdx.x;
    const float4* Wt4 = (const float4*)Wt;
    float4* Ws4 = (float4*)Ws;
    #pragma unroll 4
    for (int i = t; i < D * D / 4; i += 256) Ws4[i] = Wt4[i];
    int row0 = blockIdx.x * 32;
    const float4* x4 = (const float4*)(x + (size_t)row0 * D);
    float4* Ys4 = (float4*)Ys;
    #pragma unroll 2
    for (int i = t; i < 32 * D / 4; i += 256) {
        int c4 = (i & 31) * 4;
        float4 v = x4[i];
        v.x = fmaxf(fmaf(v.x, scale[c4 + 0], shift[c4 + 0]), 0.f);
        v.y = fmaxf(fmaf(v.y, scale[c4 + 1], shift[c4 + 1]), 0.f);
        v.z = fmaxf(fmaf(v.z, scale[c4 + 2], shift[c4 + 2]), 0.f);
        v.w = fmaxf(fmaf(v.w, scale[c4 + 3], shift[c4 + 3]), 0.f);
        Ys4[i] = v;
    }
    __syncthreads();
    int cg2 = t & 31;
    int rg = t >> 5;
    float4 acc[4] = {{0,0,0,0},{0,0,0,0},{0,0,0,0},{0,0,0,0}};
    #pragma unroll 2
    for (int k = 0; k < D; k += 4) {
        float4 w0 = *(const float4*)&Ws[(k + 0) * D + cg2 * 4];
        float4 w1 = *(const float4*)&Ws[(k + 1) * D + cg2 * 4];
        float4 w2 = *(const float4*)&Ws[(k + 2) * D + cg2 * 4];
        float4 w3 = *(const float4*)&Ws[(k + 3) * D + cg2 * 4];
        #pragma unroll
        for (int r = 0; r < 4; r++) {
            float4 y = *(const float4*)&Ys[(rg * 4 + r) * D + k];
            acc[r].x = fmaf(y.x, w0.x, fmaf(y.y, w1.x, fmaf(y.z, w2.x, fmaf(y.w, w3.x, acc[r].x))));
            acc[r].y = fmaf(y.x, w0.y, fmaf(y.y, w1.y, fmaf(y.z, w2.y, fmaf(y.w, w3.y, acc[r].y))));
            acc[r].z = fmaf(y.x, w0.z, fmaf(y.y, w1.z, fmaf(y.z, w2.z, fmaf(y.w, w3.z, acc[r].z))));
            acc[r].w = fmaf(y.x, w0.w, fmaf(y.y, w1.w, fmaf(y.z, w2.w, fmaf(y.w, w3.w, acc[r].w))));
        }
    }
    #pragma unroll
    for (int r = 0; r < 4; r++) {
        size_t row = (size_t)row0 + rg * 4 + r;
        float4 v = acc[r];
        *(float4*)&h[row * D + cg2 * 4] = v;
        if (WRITE_SQ) {
            float4 sqv = {v.x * v.x, v.y * v.y, v.z * v.z, v.w * v.w};
            *(float4*)&out[row * D + cg2 * 4] = sqv;
        }
    }
}

__global__ __launch_bounds__(256) void hist_kernel(const int* __restrict__ ei,
                                                   int* __restrict__ deg) {
    int e = blockIdx.x * 256 + threadIdx.x;
    if (e < N_EDGES) atomicAdd(&deg[ei[e]], 1);
}

__global__ __launch_bounds__(1024) void scan_kernel(const int* __restrict__ deg,
                                                    int* __restrict__ row_ptr,
                                                    int* __restrict__ cursor) {
    __shared__ int part[1024];
    int t = threadIdx.x;
    const int CHUNK = 100;
    int base = t * CHUNK;
    int s = 0;
    if (base < N_NODES) {
        for (int i = 0; i < CHUNK; i++) s += deg[base + i];
    }
    part[t] = s;
    __syncthreads();
    for (int off = 1; off < 1024; off <<= 1) {
        int v = (t >= off) ? part[t - off] : 0;
        __syncthreads();
        part[t] += v;
        __syncthreads();
    }
    int pre = (t == 0) ? 0 : part[t - 1];
    if (base < N_NODES) {
        for (int i = 0; i < CHUNK; i++) {
            row_ptr[base + i] = pre;
            cursor[base + i] = pre;
            pre += deg[base + i];
        }
    }
    if (t == 1023) row_ptr[N_NODES] = part[1023];
}

__global__ __launch_bounds__(256) void fill_kernel(const int* __restrict__ ei,
                                                   const float* __restrict__ ew,
                                                   int* __restrict__ cursor,
                                                   int* __restrict__ csr_col,
                                                   float* __restrict__ csr_w) {
    int e = blockIdx.x * 256 + threadIdx.x;
    if (e >= N_EDGES) return;
    int r = ei[e];
    int c = ei[N_EDGES + e];
    int slot = atomicAdd(&cursor[r], 1);
    csr_col[slot] = c;
    csr_w[slot] = ew[e];
}

__global__ __launch_bounds__(256) void gather_kernel(const int* __restrict__ row_ptr,
                                                     const int* __restrict__ csr_col,
                                                     const float* __restrict__ csr_w,
                                                     const float* __restrict__ h,
                                                     float* __restrict__ out) {
    int lane = threadIdx.x & 31;
    int n = blockIdx.x * 8 + (threadIdx.x >> 5);
    if (n >= N_NODES) return;
    int s0 = row_ptr[n];
    int s1 = row_ptr[n + 1];
    float4 acc = {0.f, 0.f, 0.f, 0.f};
    for (int s = s0; s < s1; s++) {
        int c = csr_col[s];
        float w = csr_w[s];
        float4 v = *(const float4*)&h[(size_t)c * D + lane * 4];
        acc.x = fmaf(w, v.x, acc.x);
        acc.y = fmaf(w, v.y, acc.y);
        acc.z = fmaf(w, v.z, acc.z);
        acc.w = fmaf(w, v.w, acc.w);
    }
    float4 hv = *(const float4*)&h[(size_t)n * D + lane * 4];
    float4 o;
    o.x = fmaf(hv.x, hv.x, acc.x);
    o.y = fmaf(hv.y, hv.y, acc.y);
    o.z = fmaf(hv.z, hv.z, acc.z);
    o.w = fmaf(hv.w, hv.w, acc.w);
    *(float4*)&out[(size_t)n * D + lane * 4] = o;
}

__global__ __launch_bounds__(256) void scatter_kernel(const int* __restrict__ ei,
                                                      const float* __restrict__ ew,
                                                      const float* __restrict__ h,
                                                      float* __restrict__ out) {
    int lane = threadIdx.x & 31;
    int e = blockIdx.x * 8 + (threadIdx.x >> 5);
    if (e >= N_EDGES) return;
    int r = ei[e];
    int c = ei[N_EDGES + e];
    float w = ew[e];
    float4 v = *(const float4*)&h[(size_t)c * D + lane * 4];
    float* o = out + (size_t)r * D + lane * 4;
    atomicAdd(o + 0, v.x * w);
    atomicAdd(o + 1, v.y * w);
    atomicAdd(o + 2, v.z * w);
    atomicAdd(o + 3, v.w * w);
}

extern "C" void kernel_launch(void* const* d_in, const int* in_sizes, int n_in,
                              void* d_out, int out_size, void* d_ws, size_t ws_size,
                              hipStream_t stream) {
    const float* n_feat = (const float*)d_in[0];
    const int*   ei     = (const int*)d_in[1];
    const float* ew     = (const float*)d_in[2];
    const float* gamma  = (const float*)d_in[3];
    const float* beta   = (const float*)d_in[4];
    const float* W      = (const float*)d_in[5];
    float* out = (float*)d_out;

    float* ws    = (float*)d_ws;
    float* stats = ws + WS_STATS;

    bool ell_ok = ws_size >= (size_t)WS_ELL_END2 * sizeof(float);
    bool csr_ok = ws_size >= (size_t)WS_END * sizeof(float);

    (void)hipMemsetAsync(stats, 0, NSTAT * 256 * sizeof(float), stream);

    if (ell_ok) {
        unsigned short* hh  = (unsigned short*)(ws + WS_HB);
        int*  deg  = (int*)ws + WS_DEG2;
        int2* ell2 = (int2*)((int*)ws + WS_ELL2);
        unsigned short* Wb = (unsigned short*)(ws + WS_WB);

        (void)hipMemsetAsync(deg, 0, N_NODES * sizeof(int), stream);
        fused_pre_kernel<<<CS_BLOCKS + FILL_BLOCKS + 16, 256, 0, stream>>>(
            n_feat, stats, ei, ew, deg, ell2, W, Wb);
        gemm_mfma7_kernel<<<(N_NODES + 63) / 64, 256, 0, stream>>>(n_feat, stats, gamma, beta, Wb, hh);
        gather_ell7_kernel<<<(N_NODES + 15) / 16, 256, 0, stream>>>(deg, ell2, hh, out);
    } else if (csr_ok) {
        float* scale = ws + WS_SCALE;
        float* shift = ws + WS_SHIFT;
        float* Wt    = ws + WS_WT;
        float* h     = ws + WS_H;
        int*   deg     = (int*)ws + WS_DEG;
        int*   row_ptr = (int*)ws + WS_ROWPTR;
        int*   cursor  = (int*)ws + WS_CURSOR;
        int*   csr_col = (int*)ws + WS_CSRCOL;
        float* csr_w   = ws + WS_CSRW;

        colstats_kernel<<<CS_BLOCKS, 256, 0, stream>>>(n_feat, stats, nullptr);
        finalize_kernel<<<1, 128, 0, stream>>>(stats, gamma, beta, scale, shift);
        transposeW_kernel<<<64, 256, 0, stream>>>(W, Wt);
        (void)hipMemsetAsync(deg, 0, N_NODES * sizeof(int), stream);
        gemm_kernel<0><<<N_NODES / 32, 256, 0, stream>>>(n_feat, scale, shift, Wt, h, out);
        hist_kernel<<<(N_EDGES + 255) / 256, 256, 0, stream>>>(ei, deg);
        scan_kernel<<<1, 1024, 0, stream>>>(deg, row_ptr, cursor);
        fill_kernel<<<(N_EDGES + 255) / 256, 256, 0, stream>>>(ei, ew, cursor, csr_col, csr_w);
        gather_kernel<<<(N_NODES + 7) / 8, 256, 0, stream>>>(row_ptr, csr_col, csr_w, h, out);
    } else {
        float* scale = ws + WS_SCALE;
        float* shift = ws + WS_SHIFT;
        float* Wt    = ws + WS_WT;
        float* h     = ws + WS_H;
        colstats_kernel<<<CS_BLOCKS, 256, 0, stream>>>(n_feat, stats, nullptr);
        finalize_kernel<<<1, 128, 0, stream>>>(stats, gamma, beta, scale, shift);
        transposeW_kernel<<<64, 256, 0, stream>>>(W, Wt);
        gemm_kernel<1><<<N_NODES / 32, 256, 0, stream>>>(n_feat, scale, shift, Wt, h, out);
        scatter_kernel<<<(N_EDGES + 7) / 8, 256, 0, stream>>>(ei, ew, h, out);
    }
}

// Round 11
// 193.085 us; speedup vs baseline: 2.5370x; 1.0073x over previous
//
#include <hip/hip_runtime.h>

#define N_NODES 100000
#define N_EDGES 400000
#define D 128
#define BN_EPS 1e-5f
#define ELL_CAP 32

#define NSTAT 64                                     // striped stat copies (atomic decongestion)
#define CS_BLOCKS 625                                // 625*256 = 160000 threads
#define CS_ITER 20                                   // 3.2M float4 / 160k = exactly 20/thread
#define FILL_BLOCKS 1563                             // ceil(400000/256)
#define GEMM_BLOCKS 782                              // 2 tiles of 64 rows per block (1563 tiles)

// ===== primary (ELL2/fp16-h) ws layout, 4B units =====
// stats and deg are ADJACENT so ONE memset clears both (466KB).
#define WS_STATS   0                                 // NSTAT*256 floats (64KB)
#define WS_DEG2    (NSTAT * 256)                     // 100000 ints
#define WS_HB      (WS_DEG2 + N_NODES)               // N*D fp16 = 6.4M float slots (16B-aligned: 116384*4%16==0)
#define WS_ELL2    (WS_HB + N_NODES * D / 2)         // N*ELL_CAP int2 = 6.4M ints
#define WS_ELL2_END (WS_ELL2 + N_NODES * ELL_CAP * 2)
#define WS_WB      WS_ELL2_END                       // W as bf16: 16384 ushort = 8192 slots
#define WS_ELL_END2 (WS_WB + 8192)
// ===== CSR fallback layout (proven R3; alternative layout, never concurrent) =====
#define WS_SCALE   (NSTAT * 256)
#define WS_SHIFT   (WS_SCALE + 128)
#define WS_WT      (WS_SHIFT + 128)
#define WS_H       (WS_WT + D * D)
#define WS_DEG     (WS_H + N_NODES * D)
#define WS_ROWPTR  (WS_DEG + N_NODES)
#define WS_CURSOR  (WS_ROWPTR + N_NODES + 1)
#define WS_CSRCOL  (WS_CURSOR + N_NODES)
#define WS_CSRW    (WS_CSRCOL + N_EDGES)
#define WS_END     (WS_CSRW + N_EDGES)

typedef __attribute__((ext_vector_type(8))) short short8;
typedef __attribute__((ext_vector_type(4))) float f32x4;

static __device__ __forceinline__ unsigned short f2bf(float f) {
    union { float f; unsigned u; } v; v.f = f;
    unsigned r = v.u + 0x7FFF + ((v.u >> 16) & 1);   // RNE
    return (unsigned short)(r >> 16);
}
static __device__ __forceinline__ float bf2f(unsigned short b) {
    union { unsigned u; float f; } v; v.u = ((unsigned)b) << 16;
    return v.f;
}
static __device__ __forceinline__ unsigned short f2h(float f) {
    union { _Float16 h; unsigned short u; } v; v.h = (_Float16)f;   // v_cvt_f16_f32, RNE
    return v.u;
}
static __device__ __forceinline__ float h2f(unsigned short u) {
    union { unsigned short u; _Float16 h; } v; v.u = u;
    return (float)v.h;
}

// ---------------- fused pre-stage: colstats || ell2-fill || convW ----------------
__global__ __launch_bounds__(256) void fused_pre_kernel(const float* __restrict__ x,
                                                        float* __restrict__ stats,
                                                        const int* __restrict__ ei,
                                                        const float* __restrict__ ew,
                                                        int* __restrict__ deg,
                                                        int2* __restrict__ ell2,
                                                        const float* __restrict__ W,
                                                        unsigned short* __restrict__ Wb) {
    int b = blockIdx.x;
    int t = threadIdx.x;
    if (b < CS_BLOCKS) {
        int tid = b * 256 + t;
        const int NTH = CS_BLOCKS * 256;             // 160000
        const float4* x4 = (const float4*)x;
        float4 v[CS_ITER];
        #pragma unroll
        for (int i = 0; i < CS_ITER; i++) v[i] = x4[tid + i * NTH];
        __builtin_amdgcn_sched_barrier(0);
        float4 s = {0.f, 0.f, 0.f, 0.f};
        float4 q = {0.f, 0.f, 0.f, 0.f};
        #pragma unroll
        for (int i = 0; i < CS_ITER; i++) {
            s.x += v[i].x; s.y += v[i].y; s.z += v[i].z; s.w += v[i].w;
            q.x += v[i].x * v[i].x; q.y += v[i].y * v[i].y;
            q.z += v[i].z * v[i].z; q.w += v[i].w * v[i].w;
        }
        __shared__ float4 ss[256];
        __shared__ float4 sq[256];
        ss[t] = s;
        sq[t] = q;
        __syncthreads();
        if (t < 32) {
            float4 a = ss[t];
            float4 bb = sq[t];
            for (int i = 32; i < 256; i += 32) {
                float4 t1 = ss[t + i];
                float4 t2 = sq[t + i];
                a.x += t1.x; a.y += t1.y; a.z += t1.z; a.w += t1.w;
                bb.x += t2.x; bb.y += t2.y; bb.z += t2.z; bb.w += t2.w;
            }
            float* st = stats + (b % NSTAT) * 256;   // striped copy
            int colb = (t * 4) & 127;
            atomicAdd(&st[colb + 0], a.x);
            atomicAdd(&st[colb + 1], a.y);
            atomicAdd(&st[colb + 2], a.z);
            atomicAdd(&st[colb + 3], a.w);
            atomicAdd(&st[128 + colb + 0], bb.x);
            atomicAdd(&st[128 + colb + 1], bb.y);
            atomicAdd(&st[128 + colb + 2], bb.z);
            atomicAdd(&st[128 + colb + 3], bb.w);
        }
    } else if (b < CS_BLOCKS + FILL_BLOCKS) {
        int e = (b - CS_BLOCKS) * 256 + t;
        if (e >= N_EDGES) return;
        int r = ei[e];
        int c = ei[N_EDGES + e];
        float w = ew[e];
        int slot = atomicAdd(&deg[r], 1);
        if (slot < ELL_CAP) ell2[r * ELL_CAP + slot] = make_int2(c, __float_as_int(w));
    } else {
        int i = (b - CS_BLOCKS - FILL_BLOCKS) * 256 + t;
        float4 v = *(const float4*)(W + i * 4);
        ushort4 o;
        o.x = f2bf(v.x); o.y = f2bf(v.y); o.z = f2bf(v.z); o.w = f2bf(v.w);
        *(ushort4*)(Wb + i * 4) = o;
    }
}

// ---------------- MFMA gemm v8: 2 tiles/block (782 blocks) — amortize finalize + tail ----------------
// R10 post-mortem: sched_barrier didn't change codegen (VGPR 48 invariant); per-block fixed
// costs (finalize 128 L2-loads, x-load ramp, barriers) x 1563 blocks are the remaining
// structural overhead. Halve block count: finalize once per 2 tiles, Wb L1-hot across both.
#define YPAD 136
__global__ __launch_bounds__(256, 4) void gemm_mfma8_kernel(const float* __restrict__ x,
                                                            const float* __restrict__ stats,
                                                            const float* __restrict__ gamma,
                                                            const float* __restrict__ beta,
                                                            const unsigned short* __restrict__ Wb,
                                                            unsigned short* __restrict__ hh) {
    __shared__ __align__(16) unsigned short Yl[64 * YPAD];
    __shared__ float sscale[128];
    __shared__ float sshift[128];
    int t = threadIdx.x;
    int lane = t & 63;
    int wave = t >> 6;
    int m16  = lane & 15;
    int quad = lane >> 4;
    int wrow0 = wave * 16;
    int c4 = (t & 31) * 4;

    // fused finalize once per block (serves both tiles)
    if (t < 128) {
        float sum = 0.f, sq = 0.f;
        #pragma unroll 16
        for (int c = 0; c < NSTAT; c++) {
            sum += stats[c * 256 + t];
            sq  += stats[c * 256 + 128 + t];
        }
        float mu  = sum * (1.0f / N_NODES);
        float var = sq * (1.0f / N_NODES) - mu * mu;
        float sc  = gamma[t] * rsqrtf(var + BN_EPS);
        sscale[t] = sc;
        sshift[t] = beta[t] - mu * sc;
    }
    __syncthreads();
    float4 sc = *(const float4*)(sscale + c4);
    float4 sh = *(const float4*)(sshift + c4);

    const unsigned short* wb = Wb + m16 * D + quad * 8;            // B[k][n]=Wb[n][k]
    const unsigned short* yl = Yl + (wrow0 + m16) * YPAD + quad * 8;

    #pragma unroll
    for (int half = 0; half < 2; half++) {
        int row0 = (blockIdx.x * 2 + half) * 64;

        float4 xv[8];
        #pragma unroll
        for (int p = 0; p < 8; p++) {
            int r = (t + p * 256) >> 5;
            int grow = row0 + r;
            int srow = grow < N_NODES ? grow : N_NODES - 1;
            xv[p] = *(const float4*)(x + (size_t)srow * D + c4);
        }
        #pragma unroll
        for (int p = 0; p < 8; p++) {
            int r = (t + p * 256) >> 5;
            ushort4 y;
            y.x = f2bf(fmaxf(fmaf(xv[p].x, sc.x, sh.x), 0.f));
            y.y = f2bf(fmaxf(fmaf(xv[p].y, sc.y, sh.y), 0.f));
            y.z = f2bf(fmaxf(fmaf(xv[p].z, sc.z, sh.z), 0.f));
            y.w = f2bf(fmaxf(fmaf(xv[p].w, sc.w, sh.w), 0.f));
            *(ushort4*)(Yl + r * YPAD + c4) = y;
        }
        __syncthreads();

        f32x4 acc[8];
        #pragma unroll
        for (int nt = 0; nt < 8; nt++) acc[nt] = (f32x4){0.f, 0.f, 0.f, 0.f};

        #pragma unroll
        for (int kc = 0; kc < 4; kc++) {
            short8 a = *(const short8*)(yl + kc * 32);
            #pragma unroll
            for (int nt = 0; nt < 8; nt++) {
                short8 b = *(const short8*)(wb + nt * 16 * D + kc * 32);
                acc[nt] = __builtin_amdgcn_mfma_f32_16x16x32_bf16(a, b, acc[nt], 0, 0, 0);
            }
        }

        #pragma unroll
        for (int r = 0; r < 4; r++) {
            int grow = row0 + wrow0 + quad * 4 + r;
            if (grow < N_NODES) {
                unsigned short* hrow = hh + (size_t)grow * D + m16;
                #pragma unroll
                for (int nt = 0; nt < 8; nt++) {
                    hrow[nt * 16] = f2h(acc[nt][r]);
                }
            }
        }
        __syncthreads();   // Yl safe for next half
    }
}

// ---------------- ELL2 gather v7: R5 structure + nt out stores (proven R8/R10) ----------------
__global__ __launch_bounds__(256) void gather_ell7_kernel(const int* __restrict__ deg,
                                                          const int2* __restrict__ ell2,
                                                          const unsigned short* __restrict__ hh,
                                                          float* __restrict__ out) {
    int lane = threadIdx.x & 15;                 // 16 lanes per node
    int n = blockIdx.x * 16 + (threadIdx.x >> 4);
    if (n >= N_NODES) return;
    short8 hself = *(const short8*)(hh + (size_t)n * D + lane * 8);   // issue early
    int dg = __builtin_nontemporal_load(&deg[n]);
    if (dg > ELL_CAP) dg = ELL_CAP;
    int dg16 = dg < 16 ? dg : 16;

    int2 my = make_int2(0, 0);
    if (lane < dg16) my = ell2[n * ELL_CAP + lane];

    float acc[8] = {0.f, 0.f, 0.f, 0.f, 0.f, 0.f, 0.f, 0.f};
    int s = 0;
    for (; s + 4 <= dg16; s += 4) {
        int   c0 = __shfl(my.x, s + 0, 16); float w0 = __int_as_float(__shfl(my.y, s + 0, 16));
        int   c1 = __shfl(my.x, s + 1, 16); float w1 = __int_as_float(__shfl(my.y, s + 1, 16));
        int   c2 = __shfl(my.x, s + 2, 16); float w2 = __int_as_float(__shfl(my.y, s + 2, 16));
        int   c3 = __shfl(my.x, s + 3, 16); float w3 = __int_as_float(__shfl(my.y, s + 3, 16));
        short8 v0 = *(const short8*)(hh + (size_t)c0 * D + lane * 8);
        short8 v1 = *(const short8*)(hh + (size_t)c1 * D + lane * 8);
        short8 v2 = *(const short8*)(hh + (size_t)c2 * D + lane * 8);
        short8 v3 = *(const short8*)(hh + (size_t)c3 * D + lane * 8);
        #pragma unroll
        for (int j = 0; j < 8; j++) {
            acc[j] = fmaf(w0, h2f((unsigned short)v0[j]), acc[j]);
            acc[j] = fmaf(w1, h2f((unsigned short)v1[j]), acc[j]);
            acc[j] = fmaf(w2, h2f((unsigned short)v2[j]), acc[j]);
            acc[j] = fmaf(w3, h2f((unsigned short)v3[j]), acc[j]);
        }
    }
    for (; s < dg16; s++) {
        int c = __shfl(my.x, s, 16);
        float w = __int_as_float(__shfl(my.y, s, 16));
        short8 v = *(const short8*)(hh + (size_t)c * D + lane * 8);
        #pragma unroll
        for (int j = 0; j < 8; j++) acc[j] = fmaf(w, h2f((unsigned short)v[j]), acc[j]);
    }
    for (s = 16; s < dg; s++) {                  // astronomically rare tail (deg > 16)
        int2 cw = ell2[n * ELL_CAP + s];
        float w = __int_as_float(cw.y);
        short8 v = *(const short8*)(hh + (size_t)cw.x * D + lane * 8);
        #pragma unroll
        for (int j = 0; j < 8; j++) acc[j] = fmaf(w, h2f((unsigned short)v[j]), acc[j]);
    }

    f32x4 a, b;
    {
        float h0 = h2f((unsigned short)hself[0]); float h1 = h2f((unsigned short)hself[1]);
        float h2 = h2f((unsigned short)hself[2]); float h3 = h2f((unsigned short)hself[3]);
        float h4 = h2f((unsigned short)hself[4]); float h5 = h2f((unsigned short)hself[5]);
        float h6 = h2f((unsigned short)hself[6]); float h7 = h2f((unsigned short)hself[7]);
        a[0] = fmaf(h0, h0, acc[0]); a[1] = fmaf(h1, h1, acc[1]);
        a[2] = fmaf(h2, h2, acc[2]); a[3] = fmaf(h3, h3, acc[3]);
        b[0] = fmaf(h4, h4, acc[4]); b[1] = fmaf(h5, h5, acc[5]);
        b[2] = fmaf(h6, h6, acc[6]); b[3] = fmaf(h7, h7, acc[7]);
    }
    float* o = out + (size_t)n * D + lane * 8;
    __builtin_nontemporal_store(a, (f32x4*)o);
    __builtin_nontemporal_store(b, (f32x4*)(o + 4));
}

// ================= CSR fallback path (proven, R3) =================
__global__ __launch_bounds__(256) void colstats_kernel(const float* __restrict__ x,
                                                       float* __restrict__ stats,
                                                       int* __restrict__ deg) {
    int tid = blockIdx.x * 256 + threadIdx.x;
    if (deg && tid < N_NODES) deg[tid] = 0;
    const int NTH = CS_BLOCKS * 256;
    const float4* x4 = (const float4*)x;
    float4 v[CS_ITER];
    #pragma unroll
    for (int i = 0; i < CS_ITER; i++) v[i] = x4[tid + i * NTH];
    __builtin_amdgcn_sched_barrier(0);
    float4 s = {0.f, 0.f, 0.f, 0.f};
    float4 q = {0.f, 0.f, 0.f, 0.f};
    #pragma unroll
    for (int i = 0; i < CS_ITER; i++) {
        s.x += v[i].x; s.y += v[i].y; s.z += v[i].z; s.w += v[i].w;
        q.x += v[i].x * v[i].x; q.y += v[i].y * v[i].y;
        q.z += v[i].z * v[i].z; q.w += v[i].w * v[i].w;
    }
    __shared__ float4 ss[256];
    __shared__ float4 sq[256];
    ss[threadIdx.x] = s;
    sq[threadIdx.x] = q;
    __syncthreads();
    if (threadIdx.x < 32) {
        float4 a = ss[threadIdx.x];
        float4 b = sq[threadIdx.x];
        for (int i = 32; i < 256; i += 32) {
            float4 t1 = ss[threadIdx.x + i];
            float4 t2 = sq[threadIdx.x + i];
            a.x += t1.x; a.y += t1.y; a.z += t1.z; a.w += t1.w;
            b.x += t2.x; b.y += t2.y; b.z += t2.z; b.w += t2.w;
        }
        float* st = stats + (blockIdx.x % NSTAT) * 256;
        int colb = (threadIdx.x * 4) & 127;
        atomicAdd(&st[colb + 0], a.x);
        atomicAdd(&st[colb + 1], a.y);
        atomicAdd(&st[colb + 2], a.z);
        atomicAdd(&st[colb + 3], a.w);
        atomicAdd(&st[128 + colb + 0], b.x);
        atomicAdd(&st[128 + colb + 1], b.y);
        atomicAdd(&st[128 + colb + 2], b.z);
        atomicAdd(&st[128 + colb + 3], b.w);
    }
}

__global__ __launch_bounds__(128) void finalize_kernel(const float* __restrict__ stats,
                                                       const float* __restrict__ gamma,
                                                       const float* __restrict__ beta,
                                                       float* __restrict__ scale,
                                                       float* __restrict__ shift) {
    int d = threadIdx.x;
    float sum = 0.f, sq = 0.f;
    #pragma unroll 16
    for (int c = 0; c < NSTAT; c++) {
        sum += stats[c * 256 + d];
        sq  += stats[c * 256 + 128 + d];
    }
    float mu  = sum * (1.0f / N_NODES);
    float var = sq * (1.0f / N_NODES) - mu * mu;
    float sc  = gamma[d] * rsqrtf(var + BN_EPS);
    scale[d] = sc;
    shift[d] = beta[d] - mu * sc;
}

__global__ __launch_bounds__(256) void transposeW_kernel(const float* __restrict__ W,
                                                         float* __restrict__ Wt) {
    int i = blockIdx.x * blockDim.x + threadIdx.x;
    if (i < D * D) {
        int j = i >> 7;
        int k = i & 127;
        Wt[k * D + j] = W[i];
    }
}

template <int WRITE_SQ>
__global__ __launch_bounds__(256) void gemm_kernel(const float* __restrict__ x,
                                                   const float* __restrict__ scale,
                                                   const float* __restrict__ shift,
                                                   const float* __restrict__ Wt,
                                                   float* __restrict__ h,
                                                   float* __restrict__ out) {
    __shared__ float Ws[D * D];
    __shared__ float Ys[32 * D];
    int t = threadIdx.x;
    const float4* Wt4 = (const float4*)Wt;
    float4* Ws4 = (float4*)Ws;
    #pragma unroll 4
    for (int i = t; i < D * D / 4; i += 256) Ws4[i] = Wt4[i];
    int row0 = blockIdx.x * 32;
    const float4* x4 = (const float4*)(x + (size_t)row0 * D);
    float4* Ys4 = (float4*)Ys;
    #pragma unroll 2
    for (int i = t; i < 32 * D / 4; i += 256) {
        int c4 = (i & 31) * 4;
        float4 v = x4[i];
        v.x = fmaxf(fmaf(v.x, scale[c4 + 0], shift[c4 + 0]), 0.f);
        v.y = fmaxf(fmaf(v.y, scale[c4 + 1], shift[c4 + 1]), 0.f);
        v.z = fmaxf(fmaf(v.z, scale[c4 + 2], shift[c4 + 2]), 0.f);
        v.w = fmaxf(fmaf(v.w, scale[c4 + 3], shift[c4 + 3]), 0.f);
        Ys4[i] = v;
    }
    __syncthreads();
    int cg2 = t & 31;
    int rg = t >> 5;
    float4 acc[4] = {{0,0,0,0},{0,0,0,0},{0,0,0,0},{0,0,0,0}};
    #pragma unroll 2
    for (int k = 0; k < D; k += 4) {
        float4 w0 = *(const float4*)&Ws[(k + 0) * D + cg2 * 4];
        float4 w1 = *(const float4*)&Ws[(k + 1) * D + cg2 * 4];
        float4 w2 = *(const float4*)&Ws[(k + 2) * D + cg2 * 4];
        float4 w3 = *(const float4*)&Ws[(k + 3) * D + cg2 * 4];
        #pragma unroll
        for (int r = 0; r < 4; r++) {
            float4 y = *(const float4*)&Ys[(rg * 4 + r) * D + k];
            acc[r].x = fmaf(y.x, w0.x, fmaf(y.y, w1.x, fmaf(y.z, w2.x, fmaf(y.w, w3.x, acc[r].x))));
            acc[r].y = fmaf(y.x, w0.y, fmaf(y.y, w1.y, fmaf(y.z, w2.y, fmaf(y.w, w3.y, acc[r].y))));
            acc[r].z = fmaf(y.x, w0.z, fmaf(y.y, w1.z, fmaf(y.z, w2.z, fmaf(y.w, w3.z, acc[r].z))));
            acc[r].w = fmaf(y.x, w0.w, fmaf(y.y, w1.w, fmaf(y.z, w2.w, fmaf(y.w, w3.w, acc[r].w))));
        }
    }
    #pragma unroll
    for (int r = 0; r < 4; r++) {
        size_t row = (size_t)row0 + rg * 4 + r;
        float4 v = acc[r];
        *(float4*)&h[row * D + cg2 * 4] = v;
        if (WRITE_SQ) {
            float4 sqv = {v.x * v.x, v.y * v.y, v.z * v.z, v.w * v.w};
            *(float4*)&out[row * D + cg2 * 4] = sqv;
        }
    }
}

__global__ __launch_bounds__(256) void hist_kernel(const int* __restrict__ ei,
                                                   int* __restrict__ deg) {
    int e = blockIdx.x * 256 + threadIdx.x;
    if (e < N_EDGES) atomicAdd(&deg[ei[e]], 1);
}

__global__ __launch_bounds__(1024) void scan_kernel(const int* __restrict__ deg,
                                                    int* __restrict__ row_ptr,
                                                    int* __restrict__ cursor) {
    __shared__ int part[1024];
    int t = threadIdx.x;
    const int CHUNK = 100;
    int base = t * CHUNK;
    int s = 0;
    if (base < N_NODES) {
        for (int i = 0; i < CHUNK; i++) s += deg[base + i];
    }
    part[t] = s;
    __syncthreads();
    for (int off = 1; off < 1024; off <<= 1) {
        int v = (t >= off) ? part[t - off] : 0;
        __syncthreads();
        part[t] += v;
        __syncthreads();
    }
    int pre = (t == 0) ? 0 : part[t - 1];
    if (base < N_NODES) {
        for (int i = 0; i < CHUNK; i++) {
            row_ptr[base + i] = pre;
            cursor[base + i] = pre;
            pre += deg[base + i];
        }
    }
    if (t == 1023) row_ptr[N_NODES] = part[1023];
}

__global__ __launch_bounds__(256) void fill_kernel(const int* __restrict__ ei,
                                                   const float* __restrict__ ew,
                                                   int* __restrict__ cursor,
                                                   int* __restrict__ csr_col,
                                                   float* __restrict__ csr_w) {
    int e = blockIdx.x * 256 + threadIdx.x;
    if (e >= N_EDGES) return;
    int r = ei[e];
    int c = ei[N_EDGES + e];
    int slot = atomicAdd(&cursor[r], 1);
    csr_col[slot] = c;
    csr_w[slot] = ew[e];
}

__global__ __launch_bounds__(256) void gather_kernel(const int* __restrict__ row_ptr,
                                                     const int* __restrict__ csr_col,
                                                     const float* __restrict__ csr_w,
                                                     const float* __restrict__ h,
                                                     float* __restrict__ out) {
    int lane = threadIdx.x & 31;
    int n = blockIdx.x * 8 + (threadIdx.x >> 5);
    if (n >= N_NODES) return;
    int s0 = row_ptr[n];
    int s1 = row_ptr[n + 1];
    float4 acc = {0.f, 0.f, 0.f, 0.f};
    for (int s = s0; s < s1; s++) {
        int c = csr_col[s];
        float w = csr_w[s];
        float4 v = *(const float4*)&h[(size_t)c * D + lane * 4];
        acc.x = fmaf(w, v.x, acc.x);
        acc.y = fmaf(w, v.y, acc.y);
        acc.z = fmaf(w, v.z, acc.z);
        acc.w = fmaf(w, v.w, acc.w);
    }
    float4 hv = *(const float4*)&h[(size_t)n * D + lane * 4];
    float4 o;
    o.x = fmaf(hv.x, hv.x, acc.x);
    o.y = fmaf(hv.y, hv.y, acc.y);
    o.z = fmaf(hv.z, hv.z, acc.z);
    o.w = fmaf(hv.w, hv.w, acc.w);
    *(float4*)&out[(size_t)n * D + lane * 4] = o;
}

__global__ __launch_bounds__(256) void scatter_kernel(const int* __restrict__ ei,
                                                      const float* __restrict__ ew,
                                                      const float* __restrict__ h,
                                                      float* __restrict__ out) {
    int lane = threadIdx.x & 31;
    int e = blockIdx.x * 8 + (threadIdx.x >> 5);
    if (e >= N_EDGES) return;
    int r = ei[e];
    int c = ei[N_EDGES + e];
    float w = ew[e];
    float4 v = *(const float4*)&h[(size_t)c * D + lane * 4];
    float* o = out + (size_t)r * D + lane * 4;
    atomicAdd(o + 0, v.x * w);
    atomicAdd(o + 1, v.y * w);
    atomicAdd(o + 2, v.z * w);
    atomicAdd(o + 3, v.w * w);
}

extern "C" void kernel_launch(void* const* d_in, const int* in_sizes, int n_in,
                              void* d_out, int out_size, void* d_ws, size_t ws_size,
                              hipStream_t stream) {
    const float* n_feat = (const float*)d_in[0];
    const int*   ei     = (const int*)d_in[1];
    const float* ew     = (const float*)d_in[2];
    const float* gamma  = (const float*)d_in[3];
    const float* beta   = (const float*)d_in[4];
    const float* W      = (const float*)d_in[5];
    float* out = (float*)d_out;

    float* ws    = (float*)d_ws;
    float* stats = ws + WS_STATS;

    bool ell_ok = ws_size >= (size_t)WS_ELL_END2 * sizeof(float);
    bool csr_ok = ws_size >= (size_t)WS_END * sizeof(float);

    if (ell_ok) {
        unsigned short* hh  = (unsigned short*)(ws + WS_HB);
        int*  deg  = (int*)ws + WS_DEG2;
        int2* ell2 = (int2*)((int*)ws + WS_ELL2);
        unsigned short* Wb = (unsigned short*)(ws + WS_WB);

        // stats+deg adjacent: ONE memset clears both (466KB)
        (void)hipMemsetAsync(stats, 0, (NSTAT * 256 + N_NODES) * sizeof(float), stream);
        fused_pre_kernel<<<CS_BLOCKS + FILL_BLOCKS + 16, 256, 0, stream>>>(
            n_feat, stats, ei, ew, deg, ell2, W, Wb);
        gemm_mfma8_kernel<<<GEMM_BLOCKS, 256, 0, stream>>>(n_feat, stats, gamma, beta, Wb, hh);
        gather_ell7_kernel<<<(N_NODES + 15) / 16, 256, 0, stream>>>(deg, ell2, hh, out);
    } else if (csr_ok) {
        float* scale = ws + WS_SCALE;
        float* shift = ws + WS_SHIFT;
        float* Wt    = ws + WS_WT;
        float* h     = ws + WS_H;
        int*   deg     = (int*)ws + WS_DEG;
        int*   row_ptr = (int*)ws + WS_ROWPTR;
        int*   cursor  = (int*)ws + WS_CURSOR;
        int*   csr_col = (int*)ws + WS_CSRCOL;
        float* csr_w   = ws + WS_CSRW;

        (void)hipMemsetAsync(stats, 0, NSTAT * 256 * sizeof(float), stream);
        colstats_kernel<<<CS_BLOCKS, 256, 0, stream>>>(n_feat, stats, nullptr);
        finalize_kernel<<<1, 128, 0, stream>>>(stats, gamma, beta, scale, shift);
        transposeW_kernel<<<64, 256, 0, stream>>>(W, Wt);
        (void)hipMemsetAsync(deg, 0, N_NODES * sizeof(int), stream);
        gemm_kernel<0><<<N_NODES / 32, 256, 0, stream>>>(n_feat, scale, shift, Wt, h, out);
        hist_kernel<<<(N_EDGES + 255) / 256, 256, 0, stream>>>(ei, deg);
        scan_kernel<<<1, 1024, 0, stream>>>(deg, row_ptr, cursor);
        fill_kernel<<<(N_EDGES + 255) / 256, 256, 0, stream>>>(ei, ew, cursor, csr_col, csr_w);
        gather_kernel<<<(N_NODES + 7) / 8, 256, 0, stream>>>(row_ptr, csr_col, csr_w, h, out);
    } else {
        float* scale = ws + WS_SCALE;
        float* shift = ws + WS_SHIFT;
        float* Wt    = ws + WS_WT;
        float* h     = ws + WS_H;
        (void)hipMemsetAsync(stats, 0, NSTAT * 256 * sizeof(float), stream);
        colstats_kernel<<<CS_BLOCKS, 256, 0, stream>>>(n_feat, stats, nullptr);
        finalize_kernel<<<1, 128, 0, stream>>>(stats, gamma, beta, scale, shift);
        transposeW_kernel<<<64, 256, 0, stream>>>(W, Wt);
        gemm_kernel<1><<<N_NODES / 32, 256, 0, stream>>>(n_feat, scale, shift, Wt, h, out);
        scatter_kernel<<<(N_EDGES + 7) / 8, 256, 0, stream>>>(ei, ew, h, out);
    }
}